// Round 17
// baseline (1122.623 us; speedup 1.0000x reference)
//
#include <hip/hip_runtime.h>
#include <hip/hip_fp16.h>
#include <hip/hip_cooperative_groups.h>

namespace cg = cooperative_groups;

#define N_NODES 100000
#define N_EDGES 1600000
#define F 64
#define NCLS 16
#define K1 8
#define BSH 9                  // bucket = row >> 9  (512 rows)
#define NBK 196                // ceil(100000 / 512)
#define BROWS 512
#define BKCAP 9216             // mean 8192 + ~11 sigma
#define EPB 4096               // bucketA edges per block
#define COLBITS 17             // N_NODES < 2^17

using f16x8 = __attribute__((ext_vector_type(8))) _Float16;
using f32x4 = __attribute__((ext_vector_type(4))) float;

// ---------------- pass A: bucket edges, 4 B packed (row_local<<17 | col) ----------------
__global__ __launch_bounds__(256) void k_bucketA(const int* __restrict__ ei,
                                                 int* __restrict__ gcur,
                                                 unsigned* __restrict__ bk) {
    __shared__ int cnt[4][256];
    __shared__ int wbase[4][256];
    int tid = threadIdx.x;
    int w = tid >> 6;
    for (int i = tid; i < 1024; i += 256) ((int*)cnt)[i] = 0;
    __syncthreads();
    unsigned pe[16];
    int packed[16];
    int e0 = blockIdx.x * EPB;
#pragma unroll
    for (int u = 0; u < 16; u++) {
        int e = e0 + u * 256 + tid;
        packed[u] = -1;
        if (e < N_EDGES) {
            int r = ei[e], c = ei[N_EDGES + e];
            if (r != c) {
                int b = r >> BSH;
                pe[u] = ((unsigned)(r & (BROWS - 1)) << COLBITS) | (unsigned)c;
                int rank = atomicAdd(&cnt[w][b], 1);
                packed[u] = (rank << 8) | b;
            }
        }
    }
    __syncthreads();
    {
        int c0 = cnt[0][tid], c1 = cnt[1][tid], c2 = cnt[2][tid], c3 = cnt[3][tid];
        int tot = c0 + c1 + c2 + c3;
        int g = tot ? atomicAdd(&gcur[tid], tot) : 0;
        wbase[0][tid] = g;
        wbase[1][tid] = g + c0;
        wbase[2][tid] = g + c0 + c1;
        wbase[3][tid] = g + c0 + c1 + c2;
    }
    __syncthreads();
#pragma unroll
    for (int u = 0; u < 16; u++) {
        if (packed[u] >= 0) {
            int b = packed[u] & 255;
            int rank = packed[u] >> 8;
            bk[(size_t)b * BKCAP + wbase[w][b] + rank] = pe[u];
        }
    }
}

// ---------------- pass B (fused): hist + scan + LDS counting-sort -> coalesced CSR ----------------
__global__ __launch_bounds__(256) void k_csrB(const unsigned* __restrict__ bk,
                                              const int* __restrict__ gcur,
                                              int* __restrict__ deg,
                                              float* __restrict__ dinv,
                                              int* __restrict__ rowptr,
                                              int* __restrict__ csr_col) {
    __shared__ int hist[BROWS];      // reused as rowoff after scan
    __shared__ int cur[BROWS];
    __shared__ int sd[256];
    __shared__ int sorted[BKCAP];
    int b = blockIdx.x;
    int tid = threadIdx.x;
    for (int i = tid; i < BROWS; i += 256) { hist[i] = 0; cur[i] = 0; }
    __syncthreads();
    int cnt = gcur[b];
    const unsigned* src = bk + (size_t)b * BKCAP;
    for (int i = tid; i < cnt; i += 256)
        atomicAdd(&hist[src[i] >> COLBITS], 1);
    __syncthreads();
    int v0 = hist[2 * tid], v1 = hist[2 * tid + 1];
    int s = v0 + v1;
    sd[tid] = s;
    __syncthreads();
    for (int d = 1; d < 256; d <<= 1) {
        int t = (tid >= d) ? sd[tid - d] : 0;
        __syncthreads();
        sd[tid] += t;
        __syncthreads();
    }
    int excl = sd[tid] - s;
    int rbase = b << BSH;
    int cbase = b * BKCAP;
    int gr0 = rbase + 2 * tid;
    int gr1 = gr0 + 1;
    if (gr0 < N_NODES) {
        deg[gr0] = v0;
        dinv[gr0] = v0 > 0 ? rsqrtf((float)v0) : 0.f;
        rowptr[gr0] = cbase + excl;
    }
    if (gr1 < N_NODES) {
        deg[gr1] = v1;
        dinv[gr1] = v1 > 0 ? rsqrtf((float)v1) : 0.f;
        rowptr[gr1] = cbase + excl + v0;
    }
    __syncthreads();
    hist[2 * tid] = excl;            // rowoff
    hist[2 * tid + 1] = excl + v0;
    __syncthreads();
    for (int i = tid; i < cnt; i += 256) {
        unsigned e = src[i];
        int rl = e >> COLBITS;
        int pos = hist[rl] + atomicAdd(&cur[rl], 1);
        sorted[pos] = (int)(e & ((1u << COLBITS) - 1));
    }
    __syncthreads();
    for (int i = tid; i < cnt; i += 256)
        csr_col[cbase + i] = sorted[i];
}

// ---------------- shared prop body (used by k_prop and k_mega) ----------------
__device__ __forceinline__ void prop_body(int wp, int lane,
                                          const int* __restrict__ rowptr,
                                          const int* __restrict__ deg,
                                          const int* __restrict__ csr_col,
                                          const float* __restrict__ dinv,
                                          const __half* __restrict__ src,
                                          const __half* __restrict__ prev,
                                          __half* __restrict__ dst,
                                          float alpha, float beta) {
    int nA = wp * 2;
    int h = lane >> 5;           // 0 = node A, 1 = node B
    int hl = lane & 31;
    int s3 = (lane >> 3) & 3;    // row slot within half
    int fb = (lane & 7) * 8;     // feature base (8 fp16 = 16 B)
    int node = nA + h;
    bool valid = node < N_NODES;
    int cb  = valid ? rowptr[node] : 0;
    int end = valid ? cb + deg[node] : 0;
    float dn = valid ? dinv[node] : 0.f;

    float acc[8] = {};

    while (true) {
        int n_own = end - cb;
        if (n_own > 32) n_own = 32;
        if (n_own < 0) n_own = 0;
        int n_oth = __shfl(n_own, lane ^ 32, 64);
        int nmax = n_own > n_oth ? n_own : n_oth;
        if (nmax == 0) break;
        int col = 0;
        float dv = 0.f;
        if (hl < n_own) {
            col = csr_col[cb + hl];
            dv = dinv[col];
        }
        for (int j = 0; j < nmax; j += 16) {
            int cc[4];
            float ww[4];
#pragma unroll
            for (int g = 0; g < 4; g++) {
                int sl = (h << 5) | (j + g * 4 + s3);
                cc[g] = __shfl(col, sl, 64);
                ww[g] = __shfl(dv, sl, 64);
            }
            uint4 raw[4];
#pragma unroll
            for (int g = 0; g < 4; g++)
                raw[g] = *(const uint4*)(src + (size_t)cc[g] * F + fb);
#pragma unroll
            for (int g = 0; g < 4; g++) {
                float2 f0 = __half22float2(*(__half2*)&raw[g].x);
                float2 f1 = __half22float2(*(__half2*)&raw[g].y);
                float2 f2 = __half22float2(*(__half2*)&raw[g].z);
                float2 f3 = __half22float2(*(__half2*)&raw[g].w);
                acc[0] = fmaf(ww[g], f0.x, acc[0]);
                acc[1] = fmaf(ww[g], f0.y, acc[1]);
                acc[2] = fmaf(ww[g], f1.x, acc[2]);
                acc[3] = fmaf(ww[g], f1.y, acc[3]);
                acc[4] = fmaf(ww[g], f2.x, acc[4]);
                acc[5] = fmaf(ww[g], f2.y, acc[5]);
                acc[6] = fmaf(ww[g], f3.x, acc[6]);
                acc[7] = fmaf(ww[g], f3.y, acc[7]);
            }
        }
        cb += n_own;
    }

#pragma unroll
    for (int i = 0; i < 8; i++) {
        acc[i] += __shfl_xor(acc[i], 8, 64);
        acc[i] += __shfl_xor(acc[i], 16, 64);
    }

    if ((lane & 24) == 0 && valid) {
        float scale = -alpha * dn;
        float r[8];
#pragma unroll
        for (int i = 0; i < 8; i++) r[i] = scale * acc[i];
        if (beta != 0.f) {
            uint4 pv = *(const uint4*)(prev + (size_t)node * F + fb);
            float2 p0 = __half22float2(*(__half2*)&pv.x);
            float2 p1 = __half22float2(*(__half2*)&pv.y);
            float2 p2 = __half22float2(*(__half2*)&pv.z);
            float2 p3 = __half22float2(*(__half2*)&pv.w);
            r[0] -= beta * p0.x; r[1] -= beta * p0.y;
            r[2] -= beta * p1.x; r[3] -= beta * p1.y;
            r[4] -= beta * p2.x; r[5] -= beta * p2.y;
            r[6] -= beta * p3.x; r[7] -= beta * p3.y;
        }
        uint4 outv;
        *(__half2*)&outv.x = __floats2half2_rn(r[0], r[1]);
        *(__half2*)&outv.y = __floats2half2_rn(r[2], r[3]);
        *(__half2*)&outv.z = __floats2half2_rn(r[4], r[5]);
        *(__half2*)&outv.w = __floats2half2_rn(r[6], r[7]);
        *(uint4*)(dst + (size_t)node * F + fb) = outv;
    }
}

// ---------------- standalone kernels (fallback path, R15-proven) ----------------
__global__ void k_cvt(const float* __restrict__ x, __half* __restrict__ t0) {
    int i = blockIdx.x * blockDim.x + threadIdx.x;
    int base = i * 4;
    if (base >= N_NODES * F) return;
    float4 v = *(const float4*)&x[base];
    __half2 a = __floats2half2_rn(v.x, v.y);
    __half2 b = __floats2half2_rn(v.z, v.w);
    *(__half2*)&t0[base] = a;
    *(__half2*)&t0[base + 2] = b;
}

__global__ void k_prepW(const float* __restrict__ W1, __half* __restrict__ Wf) {
    int t = blockIdx.x * blockDim.x + threadIdx.x;
    if (t >= K1 * 2 * 4 * 64) return;
    int lane = t & 63;
    int cb = (t >> 6) & 3;
    int fg = (t >> 8) & 1;
    int kidx = t >> 9;
    int col = cb * 16 + (lane & 15);
    int kbase = fg * 32 + (lane >> 4) * 8;
    f16x8 v;
#pragma unroll
    for (int j = 0; j < 8; j++)
        v[j] = (_Float16)W1[kidx * 4096 + (kbase + j) * 64 + col];
    *(f16x8*)(Wf + (size_t)t * 8) = v;
}

__global__ __launch_bounds__(256) void k_prop(const int* __restrict__ rowptr,
                                              const int* __restrict__ deg,
                                              const int* __restrict__ csr_col,
                                              const float* __restrict__ dinv,
                                              const __half* __restrict__ src,
                                              const __half* __restrict__ prev,
                                              __half* __restrict__ dst,
                                              float alpha, float beta) {
    int wp = (int)((blockIdx.x * blockDim.x + threadIdx.x) >> 6);
    int lane = threadIdx.x & 63;
    if (wp * 2 >= N_NODES) return;
    prop_body(wp, lane, rowptr, deg, csr_col, dinv, src, prev, dst, alpha, beta);
}

// ---------------- mega cooperative kernel: cvt + prepW + 7 prop levels ----------------
__global__ __launch_bounds__(256, 4) void k_mega(const float* __restrict__ x,
                                                 const float* __restrict__ W1,
                                                 __half* __restrict__ T,
                                                 __half* __restrict__ Wf,
                                                 const int* __restrict__ rowptr,
                                                 const int* __restrict__ deg,
                                                 const int* __restrict__ csr_col,
                                                 const float* __restrict__ dinv) {
    cg::grid_group grid = cg::this_grid();
    const int gthreads = gridDim.x * blockDim.x;
    const int gtid = blockIdx.x * blockDim.x + threadIdx.x;
    const size_t TSZ = (size_t)N_NODES * F;

    // phase 0a: cvt
    for (int i = gtid; i < N_NODES * F / 4; i += gthreads) {
        int base = i * 4;
        float4 v = *(const float4*)&x[base];
        __half2 a = __floats2half2_rn(v.x, v.y);
        __half2 b = __floats2half2_rn(v.z, v.w);
        *(__half2*)&T[base] = a;
        *(__half2*)&T[base + 2] = b;
    }
    // phase 0b: prepW
    for (int t = gtid; t < K1 * 2 * 4 * 64; t += gthreads) {
        int lane = t & 63;
        int cb = (t >> 6) & 3;
        int fg = (t >> 8) & 1;
        int kidx = t >> 9;
        int col = cb * 16 + (lane & 15);
        int kbase = fg * 32 + (lane >> 4) * 8;
        f16x8 v;
#pragma unroll
        for (int j = 0; j < 8; j++)
            v[j] = (_Float16)W1[kidx * 4096 + (kbase + j) * 64 + col];
        *(f16x8*)(Wf + (size_t)t * 8) = v;
    }
    grid.sync();

    const int lane = threadIdx.x & 63;
    const int npair = (N_NODES + 1) / 2;
    const int nwaves = gthreads >> 6;
    const int wslot = gtid >> 6;

    for (int k = 1; k < K1; k++) {
        const __half* src = T + (size_t)(k - 1) * TSZ;
        const __half* prev = T + (size_t)(k >= 2 ? k - 2 : 0) * TSZ;
        __half* dst = T + (size_t)k * TSZ;
        const float alpha = (k == 1) ? 1.f : 2.f;
        const float beta = (k == 1) ? 0.f : 1.f;
        for (int wp = wslot; wp < npair; wp += nwaves)
            prop_body(wp, lane, rowptr, deg, csr_col, dinv, src, prev, dst, alpha, beta);
        grid.sync();
    }
}

// ---------------- fused MFMA: y = softmax(relu(sum_k Tk@W1k + b1) @ W2 + b2) ----------------
__global__ __launch_bounds__(256) void k_fused_mfma(const __half* __restrict__ T,
                                                    const __half* __restrict__ Wf,
                                                    const float* __restrict__ b1,
                                                    const float* __restrict__ W2,
                                                    const float* __restrict__ b2,
                                                    float* __restrict__ y) {
    __shared__ float Ht[64][65];
    __shared__ float W2l[64 * 16];
    __shared__ float b2l[16];
    int tid = threadIdx.x;
    int lane = tid & 63;
    int w = tid >> 6;
    int ln15 = lane & 15;
    int lg = lane >> 4;
    int base = blockIdx.x * 64;

    for (int j = tid; j < 64 * 16; j += 256) W2l[j] = W2[j];
    if (tid < 16) b2l[tid] = b2[tid];

    int nd = base + (w << 4) + ln15;
    if (nd > N_NODES - 1) nd = N_NODES - 1;  // clamp: garbage rows, stores guarded

    f32x4 acc0 = {0.f, 0.f, 0.f, 0.f};
    f32x4 acc1 = {0.f, 0.f, 0.f, 0.f};
    f32x4 acc2 = {0.f, 0.f, 0.f, 0.f};
    f32x4 acc3 = {0.f, 0.f, 0.f, 0.f};

    for (int s = 0; s < 16; s++) {
        int kidx = s >> 1;
        int fg = s & 1;
        f16x8 a = *(const f16x8*)(T + ((size_t)kidx * N_NODES + nd) * F + fg * 32 + lg * 8);
        const __half* wb = Wf + ((size_t)((kidx * 2 + fg) * 4) * 64 + lane) * 8;
        f16x8 b0 = *(const f16x8*)(wb);
        f16x8 b1f = *(const f16x8*)(wb + 64 * 8);
        f16x8 b2f = *(const f16x8*)(wb + 128 * 8);
        f16x8 b3f = *(const f16x8*)(wb + 192 * 8);
        acc0 = __builtin_amdgcn_mfma_f32_16x16x32_f16(a, b0, acc0, 0, 0, 0);
        acc1 = __builtin_amdgcn_mfma_f32_16x16x32_f16(a, b1f, acc1, 0, 0, 0);
        acc2 = __builtin_amdgcn_mfma_f32_16x16x32_f16(a, b2f, acc2, 0, 0, 0);
        acc3 = __builtin_amdgcn_mfma_f32_16x16x32_f16(a, b3f, acc3, 0, 0, 0);
    }

    int hrow = (w << 4) + (lg << 2);
    {
        float bb0 = b1[0 * 16 + ln15];
        float bb1 = b1[1 * 16 + ln15];
        float bb2 = b1[2 * 16 + ln15];
        float bb3 = b1[3 * 16 + ln15];
#pragma unroll
        for (int r = 0; r < 4; r++) {
            float h0 = acc0[r] + bb0;
            float h1 = acc1[r] + bb1;
            float h2 = acc2[r] + bb2;
            float h3 = acc3[r] + bb3;
            Ht[hrow + r][0 * 16 + ln15] = h0 > 0.f ? h0 : 0.f;
            Ht[hrow + r][1 * 16 + ln15] = h1 > 0.f ? h1 : 0.f;
            Ht[hrow + r][2 * 16 + ln15] = h2 > 0.f ? h2 : 0.f;
            Ht[hrow + r][3 * 16 + ln15] = h3 > 0.f ? h3 : 0.f;
        }
    }
    __syncthreads();

    int node = tid >> 2;
    int cg2 = tid & 3;
    int gnode = base + node;
    if (gnode >= N_NODES) return;
    float l0 = b2l[cg2 * 4 + 0], l1 = b2l[cg2 * 4 + 1], l2 = b2l[cg2 * 4 + 2], l3 = b2l[cg2 * 4 + 3];
    for (int f = 0; f < 64; f++) {
        float h = Ht[node][f];
        l0 = fmaf(h, W2l[f * 16 + cg2 * 4 + 0], l0);
        l1 = fmaf(h, W2l[f * 16 + cg2 * 4 + 1], l1);
        l2 = fmaf(h, W2l[f * 16 + cg2 * 4 + 2], l2);
        l3 = fmaf(h, W2l[f * 16 + cg2 * 4 + 3], l3);
    }
    float m = fmaxf(fmaxf(l0, l1), fmaxf(l2, l3));
    m = fmaxf(m, __shfl_xor(m, 1, 64));
    m = fmaxf(m, __shfl_xor(m, 2, 64));
    float e0 = expf(l0 - m), e1 = expf(l1 - m), e2 = expf(l2 - m), e3 = expf(l3 - m);
    float s = e0 + e1 + e2 + e3;
    s += __shfl_xor(s, 1, 64);
    s += __shfl_xor(s, 2, 64);
    float inv = 1.f / s;
    float4 o = make_float4(e0 * inv, e1 * inv, e2 * inv, e3 * inv);
    *(float4*)&y[(size_t)gnode * 16 + cg2 * 4] = o;
}

// ---------------- launch ----------------

extern "C" void kernel_launch(void* const* d_in, const int* in_sizes, int n_in,
                              void* d_out, int out_size, void* d_ws, size_t ws_size,
                              hipStream_t stream) {
    const float* x  = (const float*)d_in[0];
    const int*   ei = (const int*)d_in[1];
    const float* W1 = (const float*)d_in[2];
    const float* b1 = (const float*)d_in[3];
    const float* W2 = (const float*)d_in[4];
    const float* b2 = (const float*)d_in[5];
    float* y = (float*)d_out;

    char* p = (char*)d_ws;
    auto alloc = [&](size_t bytes) {
        char* q = p;
        p += (bytes + 255) & ~(size_t)255;
        return q;
    };
    int*   deg     = (int*)alloc((size_t)N_NODES * 4);
    float* dinv    = (float*)alloc((size_t)N_NODES * 4);
    int*   rowptr  = (int*)alloc((size_t)N_NODES * 4);
    int*   gcur    = (int*)alloc(256 * 4);
    int*   csr_col = (int*)alloc((size_t)NBK * BKCAP * 4);
    __half* T      = (__half*)alloc((size_t)K1 * N_NODES * F * 2);
    __half* Wf     = (__half*)alloc((size_t)K1 * 2 * 4 * 64 * 8 * 2);

    // bucket buffer (196*9216*4B = 7.2 MB) aliases T: dead before cvt writes T.
    unsigned* bk = (unsigned*)T;

    hipMemsetAsync(gcur, 0, 256 * 4, stream);

    k_bucketA<<<(N_EDGES + EPB - 1) / EPB, 256, 0, stream>>>(ei, gcur, bk);
    k_csrB<<<NBK, 256, 0, stream>>>(bk, gcur, deg, dinv, rowptr, csr_col);

    const size_t TSZ = (size_t)N_NODES * F;

    // try the cooperative mega-kernel; fall back to proven multi-dispatch path
    bool coop_done = false;
    {
        int occ = 0;
        if (hipOccupancyMaxActiveBlocksPerMultiprocessor(
                &occ, (const void*)k_mega, 256, 0) == hipSuccess && occ >= 1) {
            int dev = 0;
            hipGetDevice(&dev);
            int num_cu = 0;
            if (hipDeviceGetAttribute(&num_cu, hipDeviceAttributeMultiprocessorCount,
                                      dev) != hipSuccess || num_cu <= 0)
                num_cu = 256;
            int blocks = occ * num_cu;
            if (blocks > 2048) blocks = 2048;
            const float* ax = x;
            const float* aW1 = W1;
            __half* aT = T;
            __half* aWf = Wf;
            const int* arp = rowptr;
            const int* adeg = deg;
            const int* acc = csr_col;
            const float* adv = dinv;
            void* args[] = {&ax, &aW1, &aT, &aWf, &arp, &adeg, &acc, &adv};
            hipError_t err = hipLaunchCooperativeKernel((void*)k_mega, dim3(blocks),
                                                        dim3(256), args, 0, stream);
            coop_done = (err == hipSuccess);
        }
    }

    if (!coop_done) {
        // fallback: R15-proven separate dispatches
        __half* Tk[K1];
        for (int k = 0; k < K1; k++) Tk[k] = T + (size_t)k * TSZ;
        k_cvt<<<(N_NODES * F / 4 + 255) / 256, 256, 0, stream>>>(x, Tk[0]);
        k_prepW<<<16, 256, 0, stream>>>(W1, Wf);
        int npair = (N_NODES + 1) / 2;
        int prop_blocks = (npair + 3) / 4;
        k_prop<<<prop_blocks, 256, 0, stream>>>(rowptr, deg, csr_col, dinv,
                                                Tk[0], Tk[0], Tk[1], 1.f, 0.f);
        for (int k = 2; k < K1; k++)
            k_prop<<<prop_blocks, 256, 0, stream>>>(rowptr, deg, csr_col, dinv,
                                                    Tk[k - 1], Tk[k - 2], Tk[k], 2.f, 1.f);
    }

    int gemm_blocks = (N_NODES + 63) / 64;
    k_fused_mfma<<<gemm_blocks, 256, 0, stream>>>(T, Wf, b1, W2, b2, y);
}

// Round 18
// 301.492 us; speedup vs baseline: 3.7236x; 3.7236x over previous
//
#include <hip/hip_runtime.h>
#include <hip/hip_fp16.h>

#define N_NODES 100000
#define N_EDGES 1600000
#define F 64
#define NCLS 16
#define K1 8
#define BSH 9                  // bucket = row >> 9  (512 rows)
#define NBK 196                // ceil(100000 / 512)
#define BROWS 512
#define BKCAP 9216             // mean 8192 + ~11 sigma
#define EPB 4096               // bucketA edges per block
#define COLBITS 17             // N_NODES < 2^17
#define NBA 391                // bucketA blocks = ceil(N_EDGES/EPB)
#define NCVT 6250              // cvt blocks = N_NODES*F/4/256
#define NPREP 16               // prepW blocks = K1*2*4*64/256

using f16x8 = __attribute__((ext_vector_type(8))) _Float16;
using f32x4 = __attribute__((ext_vector_type(4))) float;

// ---------------- fused init: bucketA | cvt | prepW (disjoint in/out, one dispatch) ----------------
__global__ __launch_bounds__(256) void k_init(const int* __restrict__ ei,
                                              int* __restrict__ gcur,
                                              unsigned* __restrict__ bk,
                                              const float* __restrict__ x,
                                              __half* __restrict__ t0,
                                              const float* __restrict__ W1,
                                              __half* __restrict__ Wf) {
    int tid = threadIdx.x;
    if (blockIdx.x < NBA) {
        // ---- bucketA: 4 B packed (row_local<<17 | col), per-wave LDS counters ----
        __shared__ int cnt[4][256];
        __shared__ int wbase[4][256];
        int w = tid >> 6;
        for (int i = tid; i < 1024; i += 256) ((int*)cnt)[i] = 0;
        __syncthreads();
        unsigned pe[16];
        int packed[16];
        int e0 = blockIdx.x * EPB;
#pragma unroll
        for (int u = 0; u < 16; u++) {
            int e = e0 + u * 256 + tid;
            packed[u] = -1;
            if (e < N_EDGES) {
                int r = ei[e], c = ei[N_EDGES + e];
                if (r != c) {
                    int b = r >> BSH;
                    pe[u] = ((unsigned)(r & (BROWS - 1)) << COLBITS) | (unsigned)c;
                    int rank = atomicAdd(&cnt[w][b], 1);
                    packed[u] = (rank << 8) | b;
                }
            }
        }
        __syncthreads();
        {
            int c0 = cnt[0][tid], c1 = cnt[1][tid], c2 = cnt[2][tid], c3 = cnt[3][tid];
            int tot = c0 + c1 + c2 + c3;
            int g = tot ? atomicAdd(&gcur[tid], tot) : 0;
            wbase[0][tid] = g;
            wbase[1][tid] = g + c0;
            wbase[2][tid] = g + c0 + c1;
            wbase[3][tid] = g + c0 + c1 + c2;
        }
        __syncthreads();
#pragma unroll
        for (int u = 0; u < 16; u++) {
            if (packed[u] >= 0) {
                int b = packed[u] & 255;
                int rank = packed[u] >> 8;
                bk[(size_t)b * BKCAP + wbase[w][b] + rank] = pe[u];
            }
        }
    } else if (blockIdx.x < NBA + NCVT) {
        // ---- cvt: x fp32 -> fp16 T0 ----
        int i = (blockIdx.x - NBA) * 256 + tid;
        int base = i * 4;
        float4 v = *(const float4*)&x[base];
        __half2 a = __floats2half2_rn(v.x, v.y);
        __half2 b = __floats2half2_rn(v.z, v.w);
        *(__half2*)&t0[base] = a;
        *(__half2*)&t0[base + 2] = b;
    } else {
        // ---- prepW: W1 -> fp16 B-fragment layout ----
        int t = (blockIdx.x - NBA - NCVT) * 256 + tid;
        int lane = t & 63;
        int cb = (t >> 6) & 3;
        int fg = (t >> 8) & 1;
        int kidx = t >> 9;
        int col = cb * 16 + (lane & 15);
        int kbase = fg * 32 + (lane >> 4) * 8;
        f16x8 v;
#pragma unroll
        for (int j = 0; j < 8; j++)
            v[j] = (_Float16)W1[kidx * 4096 + (kbase + j) * 64 + col];
        *(f16x8*)(Wf + (size_t)t * 8) = v;
    }
}

// ---------------- pass B (fused): hist + scan + LDS counting-sort -> coalesced CSR ----------------
__global__ __launch_bounds__(256) void k_csrB(const unsigned* __restrict__ bk,
                                              const int* __restrict__ gcur,
                                              int* __restrict__ deg,
                                              float* __restrict__ dinv,
                                              int* __restrict__ rowptr,
                                              int* __restrict__ csr_col) {
    __shared__ int hist[BROWS];      // reused as rowoff after scan
    __shared__ int cur[BROWS];
    __shared__ int sd[256];
    __shared__ int sorted[BKCAP];
    int b = blockIdx.x;
    int tid = threadIdx.x;
    for (int i = tid; i < BROWS; i += 256) { hist[i] = 0; cur[i] = 0; }
    __syncthreads();
    int cnt = gcur[b];
    const unsigned* src = bk + (size_t)b * BKCAP;
    for (int i = tid; i < cnt; i += 256)
        atomicAdd(&hist[src[i] >> COLBITS], 1);
    __syncthreads();
    int v0 = hist[2 * tid], v1 = hist[2 * tid + 1];
    int s = v0 + v1;
    sd[tid] = s;
    __syncthreads();
    for (int d = 1; d < 256; d <<= 1) {
        int t = (tid >= d) ? sd[tid - d] : 0;
        __syncthreads();
        sd[tid] += t;
        __syncthreads();
    }
    int excl = sd[tid] - s;
    int rbase = b << BSH;
    int cbase = b * BKCAP;
    int gr0 = rbase + 2 * tid;
    int gr1 = gr0 + 1;
    if (gr0 < N_NODES) {
        deg[gr0] = v0;
        dinv[gr0] = v0 > 0 ? rsqrtf((float)v0) : 0.f;
        rowptr[gr0] = cbase + excl;
    }
    if (gr1 < N_NODES) {
        deg[gr1] = v1;
        dinv[gr1] = v1 > 0 ? rsqrtf((float)v1) : 0.f;
        rowptr[gr1] = cbase + excl + v0;
    }
    __syncthreads();
    hist[2 * tid] = excl;            // rowoff
    hist[2 * tid + 1] = excl + v0;
    __syncthreads();
    for (int i = tid; i < cnt; i += 256) {
        unsigned e = src[i];
        int rl = e >> COLBITS;
        int pos = hist[rl] + atomicAdd(&cur[rl], 1);
        sorted[pos] = (int)(e & ((1u << COLBITS) - 1));
    }
    __syncthreads();
    for (int i = tid; i < cnt; i += 256)
        csr_col[cbase + i] = sorted[i];
}

// ---------------- propagation: col-only edges, weights factorized ----------------
// acc = sum dinv[c]*src[c]; res = -alpha*dinv[node]*acc - beta*prev.
// 2 nodes/wave, 8 lanes x 16 B per row, 4 rows per load instruction per node.
__global__ __launch_bounds__(256) void k_prop(const int* __restrict__ rowptr,
                                              const int* __restrict__ deg,
                                              const int* __restrict__ csr_col,
                                              const float* __restrict__ dinv,
                                              const __half* __restrict__ src,
                                              const __half* __restrict__ prev,
                                              __half* __restrict__ dst,
                                              float alpha, float beta) {
    int wpair = (int)((blockIdx.x * blockDim.x + threadIdx.x) >> 6);
    int lane = threadIdx.x & 63;
    int nA = wpair * 2;
    if (nA >= N_NODES) return;
    int h = lane >> 5;           // 0 = node A, 1 = node B
    int hl = lane & 31;
    int s3 = (lane >> 3) & 3;    // row slot within half
    int fb = (lane & 7) * 8;     // feature base (8 fp16 = 16 B)
    int node = nA + h;
    bool valid = node < N_NODES;
    int cb  = valid ? rowptr[node] : 0;
    int end = valid ? cb + deg[node] : 0;
    float dn = valid ? dinv[node] : 0.f;

    float acc[8] = {};

    while (true) {
        int n_own = end - cb;
        if (n_own > 32) n_own = 32;
        if (n_own < 0) n_own = 0;
        int n_oth = __shfl(n_own, lane ^ 32, 64);
        int nmax = n_own > n_oth ? n_own : n_oth;
        if (nmax == 0) break;
        int col = 0;
        float dv = 0.f;
        if (hl < n_own) {
            col = csr_col[cb + hl];
            dv = dinv[col];
        }
        for (int j = 0; j < nmax; j += 16) {
            int cc[4];
            float ww[4];
#pragma unroll
            for (int g = 0; g < 4; g++) {
                int sl = (h << 5) | (j + g * 4 + s3);
                cc[g] = __shfl(col, sl, 64);
                ww[g] = __shfl(dv, sl, 64);
            }
            uint4 raw[4];
#pragma unroll
            for (int g = 0; g < 4; g++)
                raw[g] = *(const uint4*)(src + (size_t)cc[g] * F + fb);
#pragma unroll
            for (int g = 0; g < 4; g++) {
                float2 f0 = __half22float2(*(__half2*)&raw[g].x);
                float2 f1 = __half22float2(*(__half2*)&raw[g].y);
                float2 f2 = __half22float2(*(__half2*)&raw[g].z);
                float2 f3 = __half22float2(*(__half2*)&raw[g].w);
                acc[0] = fmaf(ww[g], f0.x, acc[0]);
                acc[1] = fmaf(ww[g], f0.y, acc[1]);
                acc[2] = fmaf(ww[g], f1.x, acc[2]);
                acc[3] = fmaf(ww[g], f1.y, acc[3]);
                acc[4] = fmaf(ww[g], f2.x, acc[4]);
                acc[5] = fmaf(ww[g], f2.y, acc[5]);
                acc[6] = fmaf(ww[g], f3.x, acc[6]);
                acc[7] = fmaf(ww[g], f3.y, acc[7]);
            }
        }
        cb += n_own;
    }

    // fold slots: xor 8 / xor 16 stay within the 32-lane half, preserve lane&7
#pragma unroll
    for (int i = 0; i < 8; i++) {
        acc[i] += __shfl_xor(acc[i], 8, 64);
        acc[i] += __shfl_xor(acc[i], 16, 64);
    }

    if ((lane & 24) == 0 && valid) {
        float scale = -alpha * dn;
        float r[8];
#pragma unroll
        for (int i = 0; i < 8; i++) r[i] = scale * acc[i];
        if (beta != 0.f) {
            uint4 pv = *(const uint4*)(prev + (size_t)node * F + fb);
            float2 p0 = __half22float2(*(__half2*)&pv.x);
            float2 p1 = __half22float2(*(__half2*)&pv.y);
            float2 p2 = __half22float2(*(__half2*)&pv.z);
            float2 p3 = __half22float2(*(__half2*)&pv.w);
            r[0] -= beta * p0.x; r[1] -= beta * p0.y;
            r[2] -= beta * p1.x; r[3] -= beta * p1.y;
            r[4] -= beta * p2.x; r[5] -= beta * p2.y;
            r[6] -= beta * p3.x; r[7] -= beta * p3.y;
        }
        uint4 outv;
        *(__half2*)&outv.x = __floats2half2_rn(r[0], r[1]);
        *(__half2*)&outv.y = __floats2half2_rn(r[2], r[3]);
        *(__half2*)&outv.z = __floats2half2_rn(r[4], r[5]);
        *(__half2*)&outv.w = __floats2half2_rn(r[6], r[7]);
        *(uint4*)(dst + (size_t)node * F + fb) = outv;
    }
}

// ---------------- fused MFMA: y = softmax(relu(sum_k Tk@W1k + b1) @ W2 + b2) ----------------
__global__ __launch_bounds__(256) void k_fused_mfma(const __half* __restrict__ T,
                                                    const __half* __restrict__ Wf,
                                                    const float* __restrict__ b1,
                                                    const float* __restrict__ W2,
                                                    const float* __restrict__ b2,
                                                    float* __restrict__ y) {
    __shared__ float Ht[64][65];
    __shared__ float W2l[64 * 16];
    __shared__ float b2l[16];
    int tid = threadIdx.x;
    int lane = tid & 63;
    int w = tid >> 6;
    int ln15 = lane & 15;
    int lg = lane >> 4;
    int base = blockIdx.x * 64;

    for (int j = tid; j < 64 * 16; j += 256) W2l[j] = W2[j];
    if (tid < 16) b2l[tid] = b2[tid];

    int nd = base + (w << 4) + ln15;
    if (nd > N_NODES - 1) nd = N_NODES - 1;  // clamp: garbage rows, stores guarded

    f32x4 acc0 = {0.f, 0.f, 0.f, 0.f};
    f32x4 acc1 = {0.f, 0.f, 0.f, 0.f};
    f32x4 acc2 = {0.f, 0.f, 0.f, 0.f};
    f32x4 acc3 = {0.f, 0.f, 0.f, 0.f};

    for (int s = 0; s < 16; s++) {
        int kidx = s >> 1;
        int fg = s & 1;
        f16x8 a = *(const f16x8*)(T + ((size_t)kidx * N_NODES + nd) * F + fg * 32 + lg * 8);
        const __half* wb = Wf + ((size_t)((kidx * 2 + fg) * 4) * 64 + lane) * 8;
        f16x8 b0 = *(const f16x8*)(wb);
        f16x8 b1f = *(const f16x8*)(wb + 64 * 8);
        f16x8 b2f = *(const f16x8*)(wb + 128 * 8);
        f16x8 b3f = *(const f16x8*)(wb + 192 * 8);
        acc0 = __builtin_amdgcn_mfma_f32_16x16x32_f16(a, b0, acc0, 0, 0, 0);
        acc1 = __builtin_amdgcn_mfma_f32_16x16x32_f16(a, b1f, acc1, 0, 0, 0);
        acc2 = __builtin_amdgcn_mfma_f32_16x16x32_f16(a, b2f, acc2, 0, 0, 0);
        acc3 = __builtin_amdgcn_mfma_f32_16x16x32_f16(a, b3f, acc3, 0, 0, 0);
    }

    int hrow = (w << 4) + (lg << 2);
    {
        float bb0 = b1[0 * 16 + ln15];
        float bb1 = b1[1 * 16 + ln15];
        float bb2 = b1[2 * 16 + ln15];
        float bb3 = b1[3 * 16 + ln15];
#pragma unroll
        for (int r = 0; r < 4; r++) {
            float h0 = acc0[r] + bb0;
            float h1 = acc1[r] + bb1;
            float h2 = acc2[r] + bb2;
            float h3 = acc3[r] + bb3;
            Ht[hrow + r][0 * 16 + ln15] = h0 > 0.f ? h0 : 0.f;
            Ht[hrow + r][1 * 16 + ln15] = h1 > 0.f ? h1 : 0.f;
            Ht[hrow + r][2 * 16 + ln15] = h2 > 0.f ? h2 : 0.f;
            Ht[hrow + r][3 * 16 + ln15] = h3 > 0.f ? h3 : 0.f;
        }
    }
    __syncthreads();

    int node = tid >> 2;
    int cg2 = tid & 3;
    int gnode = base + node;
    if (gnode >= N_NODES) return;
    float l0 = b2l[cg2 * 4 + 0], l1 = b2l[cg2 * 4 + 1], l2 = b2l[cg2 * 4 + 2], l3 = b2l[cg2 * 4 + 3];
    for (int f = 0; f < 64; f++) {
        float h = Ht[node][f];
        l0 = fmaf(h, W2l[f * 16 + cg2 * 4 + 0], l0);
        l1 = fmaf(h, W2l[f * 16 + cg2 * 4 + 1], l1);
        l2 = fmaf(h, W2l[f * 16 + cg2 * 4 + 2], l2);
        l3 = fmaf(h, W2l[f * 16 + cg2 * 4 + 3], l3);
    }
    float m = fmaxf(fmaxf(l0, l1), fmaxf(l2, l3));
    m = fmaxf(m, __shfl_xor(m, 1, 64));
    m = fmaxf(m, __shfl_xor(m, 2, 64));
    float e0 = expf(l0 - m), e1 = expf(l1 - m), e2 = expf(l2 - m), e3 = expf(l3 - m);
    float s = e0 + e1 + e2 + e3;
    s += __shfl_xor(s, 1, 64);
    s += __shfl_xor(s, 2, 64);
    float inv = 1.f / s;
    float4 o = make_float4(e0 * inv, e1 * inv, e2 * inv, e3 * inv);
    *(float4*)&y[(size_t)gnode * 16 + cg2 * 4] = o;
}

// ---------------- launch ----------------

extern "C" void kernel_launch(void* const* d_in, const int* in_sizes, int n_in,
                              void* d_out, int out_size, void* d_ws, size_t ws_size,
                              hipStream_t stream) {
    const float* x  = (const float*)d_in[0];
    const int*   ei = (const int*)d_in[1];
    const float* W1 = (const float*)d_in[2];
    const float* b1 = (const float*)d_in[3];
    const float* W2 = (const float*)d_in[4];
    const float* b2 = (const float*)d_in[5];
    float* y = (float*)d_out;

    char* p = (char*)d_ws;
    auto alloc = [&](size_t bytes) {
        char* q = p;
        p += (bytes + 255) & ~(size_t)255;
        return q;
    };
    int*   deg     = (int*)alloc((size_t)N_NODES * 4);
    float* dinv    = (float*)alloc((size_t)N_NODES * 4);
    int*   rowptr  = (int*)alloc((size_t)N_NODES * 4);
    int*   gcur    = (int*)alloc(256 * 4);
    int*   csr_col = (int*)alloc((size_t)NBK * BKCAP * 4);
    __half* T      = (__half*)alloc((size_t)K1 * N_NODES * F * 2);
    __half* Wf     = (__half*)alloc((size_t)K1 * 2 * 4 * 64 * 8 * 2);

    const size_t TSZ = (size_t)N_NODES * F;
    __half* Tk[K1];
    for (int k = 0; k < K1; k++) Tk[k] = T + (size_t)k * TSZ;

    // bucket buffer (7.2 MB) aliases Tk[6..7] (25.6 MB): Tk[6] is first written by
    // prop level 6, five dispatches after k_csrB last reads bk -> no conflict, and
    // k_init's cvt (writes Tk[0]) can run in the same dispatch as bucketA.
    unsigned* bk = (unsigned*)Tk[6];

    hipMemsetAsync(gcur, 0, 256 * 4, stream);

    k_init<<<NBA + NCVT + NPREP, 256, 0, stream>>>(ei, gcur, bk, x, Tk[0], W1, Wf);
    k_csrB<<<NBK, 256, 0, stream>>>(bk, gcur, deg, dinv, rowptr, csr_col);

    int npair = (N_NODES + 1) / 2;
    int prop_blocks = (npair + 3) / 4;
    k_prop<<<prop_blocks, 256, 0, stream>>>(rowptr, deg, csr_col, dinv,
                                            Tk[0], Tk[0], Tk[1], 1.f, 0.f);
    for (int k = 2; k < K1; k++)
        k_prop<<<prop_blocks, 256, 0, stream>>>(rowptr, deg, csr_col, dinv,
                                                Tk[k - 1], Tk[k - 2], Tk[k], 2.f, 1.f);

    int gemm_blocks = (N_NODES + 63) / 64;
    k_fused_mfma<<<gemm_blocks, 256, 0, stream>>>(T, Wf, b1, W2, b2, y);
}